// Round 15
// baseline (78.804 us; speedup 1.0000x reference)
//
#include <hip/hip_runtime.h>

#define NBODY 8192
#define BLOCK 256
#define SLABS 32
#define JCHUNK (NBODY / SLABS)   // 256 j-bodies per block (== BLOCK)
#define PHASE 16                 // j-bodies register-hoisted per burst
#define NPHASE (JCHUNK / PHASE)  // 16
#define SOFT2 1.0e-4f            // 0.01^2

// FINAL (session best, R9 = 78.19us, absmax 4.0). Session ledger:
//   dur = ~40us harness ws-poison fill (untouchable, 268MB @ 85% HBM)
//       + ~36us force + ~2us memset/launch.
//   Force is invariant (+/-8%) across 16 configs: occupancy {2,4,8}
//   waves/SIMD (R12/R9/R3), IPT {1,2,4} (R0/R3/R4), DS volume 4x (R4),
//   j-path LDS/SGPR/VMEM (R9/R10/R1), chain batching (R13), packed f32
//   (R2), op count 11/12/24 (R14/R9/R7), N3L symmetry (R5), atomics vs
//   partials (R0 vs R2/R4).
//   Marginal A/Bs: +12 ops/pair -> +9.9us (exactly 2cy/op @2.4GHz, R7);
//   -1 op/pair -> 0 (R14). Effective rate ~6-7 cy/wave-instr, excess is
//   additive + structure-invariant; VALUBusy 36%, conflicts 0, HBM ~1%.
// Components: R0 single-kernel direct-atomic shell (32-way, ~free) +
// R4 burst-hoist (-3us A/B) + v_rsq (trans pipe, ~free per R7).
__global__ __launch_bounds__(BLOCK, 4) void nbody_kernel(
    const float* __restrict__ pos, const float* __restrict__ mass,
    float* __restrict__ out) {
  __shared__ float4 tile[JCHUNK];

  const int t = threadIdx.x;
  const int i = blockIdx.x * BLOCK + t;
  const int j = blockIdx.y * JCHUNK + t;  // JCHUNK == BLOCK

  // Stage j-slab: one float4 (pos.xyz, mass) per thread.
  tile[t] = make_float4(pos[j * 3 + 0], pos[j * 3 + 1], pos[j * 3 + 2],
                        mass[j]);

  const float xi = pos[i * 3 + 0];
  const float yi = pos[i * 3 + 1];
  const float zi = pos[i * 3 + 2];

  __syncthreads();

  float ax = 0.f, ay = 0.f, az = 0.f;

  for (int c = 0; c < NPHASE; ++c) {
    // Burst-hoist one phase of j-bodies into registers: 16 independent
    // wave-uniform ds_read_b128, single lgkm wait (R4-proven -3us).
    float4 jt[PHASE];
#pragma unroll
    for (int u = 0; u < PHASE; ++u) jt[u] = tile[c * PHASE + u];

    // Pure-register compute: 12 full-rate ops + 1 trans per pair.
#pragma unroll
    for (int u = 0; u < PHASE; ++u) {
      float dx = jt[u].x - xi;
      float dy = jt[u].y - yi;
      float dz = jt[u].z - zi;
      float r2 = fmaf(dx, dx, fmaf(dy, dy, fmaf(dz, dz, SOFT2)));
      float inv = __builtin_amdgcn_rsqf(r2);   // v_rsq_f32
      float w = jt[u].w * ((inv * inv) * inv); // m_j * r^-3
      ax = fmaf(w, dx, ax);
      ay = fmaf(w, dy, ay);
      az = fmaf(w, dz, az);
    }
  }

  // 32 slabs contend per address (L2-side float adds; R8 showed cost only
  // appears at 128-way).
  atomicAdd(&out[i * 3 + 0], ax);
  atomicAdd(&out[i * 3 + 1], ay);
  atomicAdd(&out[i * 3 + 2], az);
}

extern "C" void kernel_launch(void* const* d_in, const int* in_sizes, int n_in,
                              void* d_out, int out_size, void* d_ws,
                              size_t ws_size, hipStream_t stream) {
  const float* pos = (const float*)d_in[0];
  const float* mass = (const float*)d_in[1];
  float* out = (float*)d_out;

  // d_out is re-poisoned to 0xAA before every launch; atomics need zeros.
  hipMemsetAsync(d_out, 0, (size_t)out_size * sizeof(float), stream);

  nbody_kernel<<<dim3(NBODY / BLOCK, SLABS), BLOCK, 0, stream>>>(pos, mass,
                                                                 out);
}